// Round 1
// baseline (670.812 us; speedup 1.0000x reference)
//
#include <hip/hip_runtime.h>
#include <math.h>

// B=16, L=512, D_MODEL=512, H=8, M=2, E=64, KMA=25, KLAM=7
// Outputs (f32, concat): out (16,512,512)=4194304 | attn (16,8,512,512)=33554432 | om_pen | th_pen

#define PI_F 3.14159265358979323846f

static constexpr long ATTN_OFF = 4194304;
static constexpr long OM_OFF   = 37748736;
static constexpr long TH_OFF   = 37748737;

// ---------------------------------------------------------------------------
// Generic batched tiled GEMM: C[z] = epilogue(A[z] @ B[z])
// BM=BN=64, BK=16, 256 threads, 4x4 per thread. All dims assumed multiples.
// TA: A[m,k] = Abase[k*lda + m]  (transposed access)
// EPI: 0=store, 1=+bias[n], 2=C+=, 3=*wrow[m]
// z -> (zb, zh) = (z/Hdiv, z%Hdiv); offsets = zb*s?b + zh*s?h
// ---------------------------------------------------------------------------
template<bool TA, int EPI>
__global__ __launch_bounds__(256)
void gemm_k(int M, int N, int K,
            const float* __restrict__ A, int lda, long sAb, long sAh,
            const float* __restrict__ Bm, int ldb, long sBb, long sBh,
            float* __restrict__ C, int ldc, long sCb, long sCh,
            const float* __restrict__ bias,
            const float* __restrict__ wrow, long sW, int Hdiv)
{
    __shared__ float As[16][68];
    __shared__ float Bs[16][68];
    const int z = blockIdx.z;
    const int zb = z / Hdiv, zh = z % Hdiv;
    A  += (long)zb * sAb + (long)zh * sAh;
    Bm += (long)zb * sBb + (long)zh * sBh;
    C  += (long)zb * sCb + (long)zh * sCh;
    const float* wp = (EPI == 3) ? (wrow + (long)z * sW) : nullptr;

    const int t  = threadIdx.x;
    const int tx = t & 15, ty = t >> 4;
    const int m0 = blockIdx.y * 64, n0 = blockIdx.x * 64;

    float acc[4][4] = {};

    for (int k0 = 0; k0 < K; k0 += 16) {
        if (TA) {
            const int kk = t >> 4, m4 = t & 15;
            float4 v = *(const float4*)(A + (long)(k0 + kk) * lda + (m0 + m4 * 4));
            *(float4*)&As[kk][m4 * 4] = v;
        } else {
            const int mm = t >> 2, k4 = t & 3;
            float4 v = *(const float4*)(A + (long)(m0 + mm) * lda + (k0 + k4 * 4));
            As[k4 * 4 + 0][mm] = v.x; As[k4 * 4 + 1][mm] = v.y;
            As[k4 * 4 + 2][mm] = v.z; As[k4 * 4 + 3][mm] = v.w;
        }
        {
            const int kk = t >> 4, n4 = t & 15;
            float4 v = *(const float4*)(Bm + (long)(k0 + kk) * ldb + (n0 + n4 * 4));
            *(float4*)&Bs[kk][n4 * 4] = v;
        }
        __syncthreads();
        #pragma unroll
        for (int kk = 0; kk < 16; kk++) {
            float a[4], b[4];
            #pragma unroll
            for (int i = 0; i < 4; i++) a[i] = As[kk][ty * 4 + i];
            #pragma unroll
            for (int j = 0; j < 4; j++) b[j] = Bs[kk][tx * 4 + j];
            #pragma unroll
            for (int i = 0; i < 4; i++)
                #pragma unroll
                for (int j = 0; j < 4; j++)
                    acc[i][j] += a[i] * b[j];
        }
        __syncthreads();
    }

    #pragma unroll
    for (int i = 0; i < 4; i++) {
        const int m = m0 + ty * 4 + i;
        float4 r = { acc[i][0], acc[i][1], acc[i][2], acc[i][3] };
        float* cp = C + (long)m * ldc + n0 + tx * 4;
        if (EPI == 1) {
            float4 bb = *(const float4*)(bias + n0 + tx * 4);
            r.x += bb.x; r.y += bb.y; r.z += bb.z; r.w += bb.w;
        }
        if (EPI == 2) {
            float4 c = *(const float4*)cp;
            r.x += c.x; r.y += c.y; r.z += c.z; r.w += c.w;
        }
        if (EPI == 3) {
            float wv = wp[m];
            r.x *= wv; r.y *= wv; r.z *= wv; r.w *= wv;
        }
        *(float4*)cp = r;
    }
}

// ---------------------------------------------------------------------------
// Skinny projection: for one input matrix X (8192x512), compute
// om = relu(X@Wom + bom) (8192x16) and th = tanh(X@Wth + bth)*PI (8192x16).
// Block: 256 = 32 cols (16 om + 16 th) x 8 rows.
// ---------------------------------------------------------------------------
__global__ __launch_bounds__(256)
void skinny_k(const float* __restrict__ X,
              const float* __restrict__ Wom, const float* __restrict__ bom,
              const float* __restrict__ Wth, const float* __restrict__ bth,
              float* __restrict__ om_out, float* __restrict__ th_out)
{
    const int t = threadIdx.x;
    const int tx = t & 31, ty = t >> 5;
    const long row = (long)blockIdx.x * 8 + ty;
    const int col = tx & 15;
    const bool isTh = tx >= 16;
    const float* __restrict__ Wm = isTh ? Wth : Wom;
    const float* __restrict__ xr = X + row * 512;
    float acc0 = 0.f, acc1 = 0.f, acc2 = 0.f, acc3 = 0.f;
    for (int k = 0; k < 512; k += 4) {
        acc0 += xr[k + 0] * Wm[(k + 0) * 16 + col];
        acc1 += xr[k + 1] * Wm[(k + 1) * 16 + col];
        acc2 += xr[k + 2] * Wm[(k + 2) * 16 + col];
        acc3 += xr[k + 3] * Wm[(k + 3) * 16 + col];
    }
    float acc = (acc0 + acc1) + (acc2 + acc3);
    if (isTh) {
        acc += bth[col];
        th_out[row * 16 + col] = tanhf(acc) * PI_F;
    } else {
        acc += bom[col];
        om_out[row * 16 + col] = fmaxf(acc, 0.f);
    }
}

// ---------------------------------------------------------------------------
// Phases: C[b,l,h, 0..3] = {cos p0, sin p0, cos p1, sin p1}, p_m = om_m*l + th_m
// ---------------------------------------------------------------------------
__global__ __launch_bounds__(256)
void phases_k(const float* __restrict__ om, const float* __restrict__ th,
              float* __restrict__ C)
{
    const int i = blockIdx.x * 256 + threadIdx.x;   // (b*512+l)*8 + h, n=65536
    if (i >= 65536) return;
    const float tt = (float)((i >> 3) & 511);
    const float o0 = om[i * 2 + 0], o1 = om[i * 2 + 1];
    const float t0 = th[i * 2 + 0], t1 = th[i * 2 + 1];
    float c0, s0, c1, s1;
    sincosf(o0 * tt + t0, &s0, &c0);
    sincosf(o1 * tt + t1, &s1, &c1);
    float4 r = { c0, s0, c1, s1 };
    *(float4*)&C[(long)i * 4] = r;
}

// ---------------------------------------------------------------------------
// Moving average (window 25, replicate pad 12) along L of (B,L,512).
// Block: 64 channels x 64 l-rows tile; sliding-window sums from LDS.
// MODE 0: RES = x - ma ; MODE 1: also TREND = ma
// ---------------------------------------------------------------------------
template<int MODE>
__global__ __launch_bounds__(256)
void movavg_k(const float* __restrict__ X, float* __restrict__ RES,
              float* __restrict__ TREND)
{
    const int b = blockIdx.z, l0 = blockIdx.y * 64, c0 = blockIdx.x * 64;
    __shared__ float sm[88][64];
    const float* __restrict__ Xb = X + (long)b * 512 * 512 + c0;
    const int t = threadIdx.x;
    for (int i = t; i < 88 * 64; i += 256) {
        const int r = i >> 6, c = i & 63;
        int gl = l0 + r - 12;
        gl = min(max(gl, 0), 511);
        sm[r][c] = Xb[(long)gl * 512 + c];
    }
    __syncthreads();
    const int tx = t & 63, ty = t >> 6;   // channel, row-group (16 rows each)
    const int rbase = ty * 16;
    float s = 0.f;
    #pragma unroll
    for (int d = 0; d < 25; d++) s += sm[rbase + d][tx];
    const float inv = 1.f / 25.f;
    #pragma unroll
    for (int r = 0; r < 16; r++) {
        const long l = l0 + rbase + r;
        const float ma = s * inv;
        const float x = sm[rbase + r + 12][tx];
        RES[((long)b * 512 + l) * 512 + c0 + tx] = x - ma;
        if (MODE) TREND[((long)b * 512 + l) * 512 + c0 + tx] = ma;
        if (r < 15) s += sm[rbase + r + 25][tx] - sm[rbase + r][tx];
    }
}

// ---------------------------------------------------------------------------
// Scores: S[b,h,l,s] = (q[b,l,h,:]·k[b,s,h,:]) * (Cq[b,l,h,:]·Ck[b,s,h,:]) / 8
// K=64 single pass. 64x64 tile per block.
// ---------------------------------------------------------------------------
__global__ __launch_bounds__(256)
void scores_k(const float* __restrict__ Q, const float* __restrict__ Kr,
              const float* __restrict__ Cq, const float* __restrict__ Ck,
              float* __restrict__ S)
{
    const int z = blockIdx.z;                 // b*8+h
    const int b = z >> 3, h = z & 7;
    const int l0 = blockIdx.y * 64, s0 = blockIdx.x * 64;
    __shared__ float Qs[64][68], Ks[64][68];  // [e][l], [e][s]
    __shared__ float Cqs[64][4], Cks[64][4];
    const float* __restrict__ Qb = Q + ((long)b * 512) * 512 + h * 64;
    const float* __restrict__ Kb = Kr + ((long)b * 512) * 512 + h * 64;
    const int t = threadIdx.x;
    #pragma unroll
    for (int i = 0; i < 4; i++) {
        const int slot = t + i * 256;         // 1024 float4 slots
        const int row = slot >> 4, e4 = slot & 15;
        float4 v = *(const float4*)(Qb + (long)(l0 + row) * 512 + e4 * 4);
        Qs[e4 * 4 + 0][row] = v.x; Qs[e4 * 4 + 1][row] = v.y;
        Qs[e4 * 4 + 2][row] = v.z; Qs[e4 * 4 + 3][row] = v.w;
        float4 u = *(const float4*)(Kb + (long)(s0 + row) * 512 + e4 * 4);
        Ks[e4 * 4 + 0][row] = u.x; Ks[e4 * 4 + 1][row] = u.y;
        Ks[e4 * 4 + 2][row] = u.z; Ks[e4 * 4 + 3][row] = u.w;
    }
    if (t < 64) {
        *(float4*)&Cqs[t][0] = *(const float4*)(Cq + ((long)((b * 512 + l0 + t) * 8 + h)) * 4);
    } else if (t < 128) {
        const int r = t - 64;
        *(float4*)&Cks[r][0] = *(const float4*)(Ck + ((long)((b * 512 + s0 + r) * 8 + h)) * 4);
    }
    __syncthreads();
    const int tx = t & 15, ty = t >> 4;
    float acc[4][4] = {};
    #pragma unroll 8
    for (int e = 0; e < 64; e++) {
        float a[4], bb[4];
        #pragma unroll
        for (int i = 0; i < 4; i++) a[i] = Qs[e][ty * 4 + i];
        #pragma unroll
        for (int j = 0; j < 4; j++) bb[j] = Ks[e][tx * 4 + j];
        #pragma unroll
        for (int i = 0; i < 4; i++)
            #pragma unroll
            for (int j = 0; j < 4; j++)
                acc[i][j] += a[i] * bb[j];
    }
    float* __restrict__ Sb = S + ((long)z * 512 + l0) * 512 + s0;
    #pragma unroll
    for (int i = 0; i < 4; i++) {
        const int l = ty * 4 + i;
        const float cq0 = Cqs[l][0], cq1 = Cqs[l][1], cq2 = Cqs[l][2], cq3 = Cqs[l][3];
        float4 r;
        float* rr = (float*)&r;
        #pragma unroll
        for (int j = 0; j < 4; j++) {
            const int ss = tx * 4 + j;
            const float mod = cq0 * Cks[ss][0] + cq1 * Cks[ss][1]
                            + cq2 * Cks[ss][2] + cq3 * Cks[ss][3];
            rr[j] = acc[i][j] * mod * 0.125f;
        }
        *(float4*)(Sb + (long)l * 512 + tx * 4) = r;
    }
}

// ---------------------------------------------------------------------------
// In-place softmax over rows of 512. One wave per row, 4 rows per block.
// ---------------------------------------------------------------------------
__global__ __launch_bounds__(256)
void softmax_k(float* __restrict__ A)
{
    const long row = (long)blockIdx.x * 4 + (threadIdx.x >> 6);
    const int lane = threadIdx.x & 63;
    float* __restrict__ r = A + row * 512;
    float v[8];
    float m = -INFINITY;
    #pragma unroll
    for (int i = 0; i < 8; i++) { v[i] = r[lane + i * 64]; m = fmaxf(m, v[i]); }
    #pragma unroll
    for (int off = 32; off; off >>= 1) m = fmaxf(m, __shfl_xor(m, off));
    float s = 0.f;
    #pragma unroll
    for (int i = 0; i < 8; i++) { v[i] = __expf(v[i] - m); s += v[i]; }
    #pragma unroll
    for (int off = 32; off; off >>= 1) s += __shfl_xor(s, off);
    const float inv = 1.f / s;
    #pragma unroll
    for (int i = 0; i < 8; i++) r[lane + i * 64] = v[i] * inv;
}

// ---------------------------------------------------------------------------
// Lambda conv + w: per (b,h): lam[l] = sum_{e,k} vt_pad[e, l+k] * Wlam[0,e,k];
// w[b,h,l] = 1 / (1 + (1 + elu(lam + blam)) * S[l])
// ---------------------------------------------------------------------------
__global__ __launch_bounds__(512)
void lamw_k(const float* __restrict__ VT, const float* __restrict__ Wlam,
            const float* __restrict__ blam, const float* __restrict__ Sv,
            float* __restrict__ Wout)
{
    const int z = blockIdx.x;                 // b*8+h
    const int b = z >> 3, h = z & 7;
    __shared__ float sv[512][17];
    __shared__ float sw[448];
    const int t = threadIdx.x;                // 512
    if (t < 448) sw[t] = Wlam[t];
    const float* __restrict__ Vb = VT + ((long)b * 512) * 512 + h * 64;
    float lam = 0.f;
    for (int ec = 0; ec < 4; ec++) {
        __syncthreads();
        #pragma unroll
        for (int j4 = 0; j4 < 4; j4++) {
            float4 v = *(const float4*)(Vb + (long)t * 512 + ec * 16 + j4 * 4);
            sv[t][j4 * 4 + 0] = v.x; sv[t][j4 * 4 + 1] = v.y;
            sv[t][j4 * 4 + 2] = v.z; sv[t][j4 * 4 + 3] = v.w;
        }
        __syncthreads();
        #pragma unroll
        for (int dk = 0; dk < 7; dk++) {
            int r = t + dk - 3;
            r = min(max(r, 0), 511);
            #pragma unroll
            for (int j = 0; j < 16; j++)
                lam += sv[r][j] * sw[(ec * 16 + j) * 7 + dk];
        }
    }
    lam += blam[0];
    const float el = lam > 0.f ? lam : expm1f(lam);
    const float wv = 1.f / (1.f + (1.f + el) * Sv[t]);
    Wout[(long)z * 512 + t] = wv;
}

// ---------------------------------------------------------------------------
// Penalties, deterministic 2-stage.
// om_pen = sum_l (x[l+1]-x[l])^2 over q_om,k_om; th_pen = sum x^2 over q_th,k_th
// ---------------------------------------------------------------------------
__global__ __launch_bounds__(256)
void pen1_k(const float* __restrict__ qom, const float* __restrict__ kom,
            const float* __restrict__ qth, const float* __restrict__ kth,
            float* __restrict__ partials)
{
    const long tid = (long)blockIdx.x * 256 + threadIdx.x;   // 65536 threads
    float om = 0.f, th = 0.f;
    for (long i = tid; i < 262144; i += 65536) {
        const float* om_arr = (i < 131072) ? qom : kom;
        const float* th_arr = (i < 131072) ? qth : kth;
        const long j = i & 131071;
        const float x = th_arr[j];
        th += x * x;
        const int l = (int)((j >> 4) & 511);
        if (l < 511) {
            const float d = om_arr[j + 16] - om_arr[j];
            om += d * d;
        }
    }
    __shared__ float som[256], sth[256];
    som[threadIdx.x] = om; sth[threadIdx.x] = th;
    __syncthreads();
    for (int o = 128; o; o >>= 1) {
        if (threadIdx.x < o) {
            som[threadIdx.x] += som[threadIdx.x + o];
            sth[threadIdx.x] += sth[threadIdx.x + o];
        }
        __syncthreads();
    }
    if (threadIdx.x == 0) {
        partials[blockIdx.x] = som[0];
        partials[256 + blockIdx.x] = sth[0];
    }
}

__global__ __launch_bounds__(256)
void pen2_k(const float* __restrict__ partials, float* __restrict__ om_out,
            float* __restrict__ th_out)
{
    __shared__ float som[256], sth[256];
    const int t = threadIdx.x;
    som[t] = partials[t]; sth[t] = partials[256 + t];
    __syncthreads();
    for (int o = 128; o; o >>= 1) {
        if (t < o) { som[t] += som[t + o]; sth[t] += sth[t + o]; }
        __syncthreads();
    }
    if (t == 0) { *om_out = som[0]; *th_out = sth[0]; }
}

// ---------------------------------------------------------------------------
extern "C" void kernel_launch(void* const* d_in, const int* in_sizes, int n_in,
                              void* d_out_v, int out_size, void* d_ws, size_t ws_size,
                              hipStream_t stream)
{
    const float* queries = (const float*)d_in[0];
    const float* keys    = (const float*)d_in[1];
    const float* values  = (const float*)d_in[2];
    const float* Wq  = (const float*)d_in[3];  const float* bq  = (const float*)d_in[4];
    const float* Wk  = (const float*)d_in[5];  const float* bk  = (const float*)d_in[6];
    const float* Wv  = (const float*)d_in[7];  const float* bv  = (const float*)d_in[8];
    const float* Wqo = (const float*)d_in[9];  const float* bqo = (const float*)d_in[10];
    const float* Wko = (const float*)d_in[11]; const float* bko = (const float*)d_in[12];
    const float* Wqt = (const float*)d_in[13]; const float* bqt = (const float*)d_in[14];
    const float* Wkt = (const float*)d_in[15]; const float* bkt = (const float*)d_in[16];
    const float* Wo  = (const float*)d_in[17]; const float* bo  = (const float*)d_in[18];
    const float* Wlam= (const float*)d_in[19]; const float* blam= (const float*)d_in[20];
    const float* U   = (const float*)d_in[21]; const float* Sv  = (const float*)d_in[22];

    float* out = (float*)d_out_v;
    float* W   = (float*)d_ws;

    // workspace layout (floats); q_proj/k_proj reused as T1/attn_out after movavg
    float* q_proj  = W;
    float* k_proj  = W + 4194304;
    float* v_proj  = W + 8388608;
    float* q_res   = W + 12582912;
    float* k_res   = W + 16777216;
    float* v_res   = W + 20971520;
    float* v_trend = W + 25165824;
    float* T1       = q_proj;
    float* attn_out = k_proj;
    float* q_om = W + 29360128;
    float* k_om = q_om + 131072;
    float* q_th = k_om + 131072;
    float* k_th = q_th + 131072;
    float* Cq   = k_th + 131072;
    float* Ck   = Cq + 262144;
    float* wbuf = Ck + 262144;
    float* partials = wbuf + 65536;

    float* attn = out + ATTN_OFF;
    dim3 blk(256);

    // 1. q/k/v projections: (8192x512)@(512x512)+bias
    gemm_k<false,1><<<dim3(8,128,1), blk, 0, stream>>>(8192,512,512,
        queries,512,0,0, Wq,512,0,0, q_proj,512,0,0, bq, nullptr,0, 1);
    gemm_k<false,1><<<dim3(8,128,1), blk, 0, stream>>>(8192,512,512,
        keys,512,0,0, Wk,512,0,0, k_proj,512,0,0, bk, nullptr,0, 1);
    gemm_k<false,1><<<dim3(8,128,1), blk, 0, stream>>>(8192,512,512,
        values,512,0,0, Wv,512,0,0, v_proj,512,0,0, bv, nullptr,0, 1);

    // 2. omega/theta skinny projections
    skinny_k<<<dim3(1024), blk, 0, stream>>>(queries, Wqo, bqo, Wqt, bqt, q_om, q_th);
    skinny_k<<<dim3(1024), blk, 0, stream>>>(keys,    Wko, bko, Wkt, bkt, k_om, k_th);

    // 3. phase cos/sin tables
    phases_k<<<dim3(256), blk, 0, stream>>>(q_om, q_th, Cq);
    phases_k<<<dim3(256), blk, 0, stream>>>(k_om, k_th, Ck);

    // 4. series decomposition
    movavg_k<0><<<dim3(8,8,16), blk, 0, stream>>>(q_proj, q_res, nullptr);
    movavg_k<0><<<dim3(8,8,16), blk, 0, stream>>>(k_proj, k_res, nullptr);
    movavg_k<1><<<dim3(8,8,16), blk, 0, stream>>>(v_proj, v_res, v_trend);

    // 5. scores (rank-4 modulated) -> attn region of d_out
    scores_k<<<dim3(8,8,128), blk, 0, stream>>>(q_res, k_res, Cq, Ck, attn);

    // 6. softmax in place
    softmax_k<<<dim3(16384), blk, 0, stream>>>(attn);

    // 7. attn @ v  -> attn_out (B,L,H*E)
    gemm_k<false,0><<<dim3(1,8,128), blk, 0, stream>>>(512,64,512,
        attn,512, 2097152,262144, v_res,512, 262144,64,
        attn_out,512, 262144,64, nullptr, nullptr,0, 8);

    // 8. lambda conv -> w
    lamw_k<<<dim3(128), dim3(512), 0, stream>>>(v_trend, Wlam, blam, Sv, wbuf);

    // 9. T1 = w ⊙ (U^T @ v_trend)
    gemm_k<true,3><<<dim3(1,8,128), blk, 0, stream>>>(512,64,512,
        U,512,0,0, v_trend,512, 262144,64, T1,64, 262144,32768,
        nullptr, wbuf,512, 8);

    // 10. attn_out += U @ T1
    gemm_k<false,2><<<dim3(1,8,128), blk, 0, stream>>>(512,64,512,
        U,512,0,0, T1,64, 262144,32768, attn_out,512, 262144,64,
        nullptr, nullptr,0, 8);

    // 11. out projection
    gemm_k<false,1><<<dim3(8,128,1), blk, 0, stream>>>(8192,512,512,
        attn_out,512,0,0, Wo,512,0,0, out,512,0,0, bo, nullptr,0, 1);

    // 12. penalties (deterministic)
    pen1_k<<<dim3(256), blk, 0, stream>>>(q_om, k_om, q_th, k_th, partials);
    pen2_k<<<dim3(1), blk, 0, stream>>>(partials, out + OM_OFF, out + TH_OFF);
}

// Round 2
// 456.644 us; speedup vs baseline: 1.4690x; 1.4690x over previous
//
#include <hip/hip_runtime.h>
#include <math.h>

// B=16, L=512, D_MODEL=512, H=8, M=2, E=64, KMA=25, KLAM=7
// Outputs (f32, concat): out (16,512,512) | attn (16,8,512,512) | om_pen | th_pen

#define PI_F 3.14159265358979323846f

typedef __attribute__((ext_vector_type(8))) short bf16x8;
typedef __attribute__((ext_vector_type(4))) float f32x4;

static constexpr long ATTN_OFF = 4194304;
static constexpr long OM_OFF   = 37748736;
static constexpr long TH_OFF   = 37748737;

// ---------------------------------------------------------------------------
// f32 -> bf16 hi/lo split helpers (RNE). hi+lo reproduces x to ~2^-17 rel.
// ---------------------------------------------------------------------------
__device__ __forceinline__ ushort f2bf(float f){
  uint u = __float_as_uint(f);
  u += 0x7fffu + ((u >> 16) & 1u);
  return (ushort)(u >> 16);
}

__device__ __forceinline__ void cvt8(const float* f, uint4 &H, uint4 &L){
  ushort h[8], l[8];
#pragma unroll
  for (int j = 0; j < 8; j++){
    h[j] = f2bf(f[j]);
    float hf = __uint_as_float((uint)h[j] << 16);
    l[j] = f2bf(f[j] - hf);
  }
  H.x = (uint)h[0] | ((uint)h[1] << 16); H.y = (uint)h[2] | ((uint)h[3] << 16);
  H.z = (uint)h[4] | ((uint)h[5] << 16); H.w = (uint)h[6] | ((uint)h[7] << 16);
  L.x = (uint)l[0] | ((uint)l[1] << 16); L.y = (uint)l[2] | ((uint)l[3] << 16);
  L.z = (uint)l[4] | ((uint)l[5] << 16); L.w = (uint)l[6] | ((uint)l[7] << 16);
}

// ---------------------------------------------------------------------------
// LDS staging. Layout per operand: [row][64 k] bf16, 128B rows, 8x16B slots,
// XOR-swizzled: physical slot = kb ^ (row&7). Frag reads are conflict-free.
// stage_rm: operand stored [row][k] contiguous-k (row-major activations)
// stage_cm: operand stored [k][row] (gather 8 coalesced dwords per (row,kb))
// stage_pre: pre-converted bf16 hi/lo, [row][K] contiguous-k
// ---------------------------------------------------------------------------
template<int ROWS>
__device__ __forceinline__ void stage_rm(const float* __restrict__ G, int ld,
                                         short* hi, short* lo, int t){
#pragma unroll
  for (int i = 0; i < ROWS*8/256; i++){
    int p = t + i*256;
    int row = p >> 3, kb = p & 7;
    const float* g = G + (long)row*ld + kb*8;
    float f[8];
    *(float4*)&f[0] = *(const float4*)g;
    *(float4*)&f[4] = *(const float4*)(g + 4);
    uint4 H, L; cvt8(f, H, L);
    int idx = row*64 + ((kb ^ (row & 7)) << 3);
    *(uint4*)&hi[idx] = H; *(uint4*)&lo[idx] = L;
  }
}

template<int ROWS>
__device__ __forceinline__ void stage_cm(const float* __restrict__ G, int ld,
                                         short* hi, short* lo, int t){
#pragma unroll
  for (int i = 0; i < ROWS*8/256; i++){
    int p = t + i*256;
    int row = p & (ROWS-1), kb = p / ROWS;
    const float* g = G + (long)kb*8*ld + row;
    float f[8];
#pragma unroll
    for (int j = 0; j < 8; j++) f[j] = g[(long)j*ld];
    uint4 H, L; cvt8(f, H, L);
    int idx = row*64 + ((kb ^ (row & 7)) << 3);
    *(uint4*)&hi[idx] = H; *(uint4*)&lo[idx] = L;
  }
}

template<int ROWS>
__device__ __forceinline__ void stage_pre(const short* __restrict__ Gh,
                                          const short* __restrict__ Gl, int ldk,
                                          short* hi, short* lo, int t){
#pragma unroll
  for (int i = 0; i < ROWS*8/256; i++){
    int p = t + i*256;
    int row = p >> 3, kb = p & 7;
    long off = (long)row*ldk + kb*8;
    uint4 H = *(const uint4*)(Gh + off);
    uint4 L = *(const uint4*)(Gl + off);
    int idx = row*64 + ((kb ^ (row & 7)) << 3);
    *(uint4*)&hi[idx] = H; *(uint4*)&lo[idx] = L;
  }
}

// ---------------------------------------------------------------------------
// MFMA GEMM, bf16 hi/lo split (3 mfma per frag pair): C = epi(A @ B)
// BK=64, 256 threads = 4 waves (WM x WN), per-wave FMxFN 16x16 frags.
// EPI: 0=store 1=+bias 2=C+= 3=*wcol[col] 4=rank-4 rotation modulation
// QKV: z in 0..2 selects (A,A1,A2), (bias,bias1,bias2), weights at z*524288
// ---------------------------------------------------------------------------
template<int BM,int BN,int WM,int WN,bool ACM,bool BCM,bool BPRE,bool QKV,int EPI>
__global__ __launch_bounds__(256)
void mgemm(int K,
  const float* __restrict__ A, const float* __restrict__ A1, const float* __restrict__ A2,
  int lda, long sAb, long sAh,
  const float* __restrict__ Bp, int ldb, long sBb, long sBh,
  const short* __restrict__ BhiP, const short* __restrict__ BloP,
  float* __restrict__ C, int ldc, long sCb, long sCh,
  const float* __restrict__ bias, const float* __restrict__ bias1, const float* __restrict__ bias2,
  const float* __restrict__ wcolp,
  const float* __restrict__ cqp, const float* __restrict__ ckp, int Hdiv)
{
  __shared__ short Ahi[BM*64], Alo[BM*64], Bhi[BN*64], Blo[BN*64];
  constexpr int WMT = BM/WM, WNT = BN/WN;
  constexpr int FM = WMT/16, FN = WNT/16;

  const int z = blockIdx.z;
  const int zb = z / Hdiv, zh = z % Hdiv;
  const float* Ab;
  if constexpr (QKV) Ab = (zb == 0) ? A : ((zb == 1) ? A1 : A2);
  else               Ab = A + (long)zb*sAb + (long)zh*sAh;
  const float* Bb = nullptr;
  const short* BhP = BhiP; const short* BlP = BloP;
  if constexpr (BPRE) { if constexpr (QKV) { BhP += (long)zb*524288; BlP += (long)zb*524288; } }
  else Bb = Bp + (long)zb*sBb + (long)zh*sBh;
  float* Cb = C + (long)zb*sCb + (long)zh*sCh;

  const int t = threadIdx.x;
  const int m0 = blockIdx.y*BM, n0 = blockIdx.x*BN;
  const int wave = t >> 6, lane = t & 63;
  const int wr = wave / WN, wc = wave % WN;
  const int lr = lane & 15, lk = lane >> 4;

  f32x4 acc[FM][FN];
#pragma unroll
  for (int mi = 0; mi < FM; mi++)
#pragma unroll
    for (int nj = 0; nj < FN; nj++) acc[mi][nj] = (f32x4){0.f, 0.f, 0.f, 0.f};

  for (int k0 = 0; k0 < K; k0 += 64){
    if constexpr (ACM) stage_cm<BM>(Ab + (long)k0*lda + m0, lda, Ahi, Alo, t);
    else               stage_rm<BM>(Ab + (long)m0*lda + k0, lda, Ahi, Alo, t);
    if constexpr (BPRE)     stage_pre<BN>(BhP + (long)n0*K + k0, BlP + (long)n0*K + k0, K, Bhi, Blo, t);
    else if constexpr (BCM) stage_cm<BN>(Bb + (long)k0*ldb + n0, ldb, Bhi, Blo, t);
    else                    stage_rm<BN>(Bb + (long)n0*ldb + k0, ldb, Bhi, Blo, t);
    __syncthreads();
#pragma unroll
    for (int kk = 0; kk < 2; kk++){
      bf16x8 ah[FM], al[FM], bh[FN], bl[FN];
#pragma unroll
      for (int mi = 0; mi < FM; mi++){
        int row = wr*WMT + mi*16 + lr;
        int idx = row*64 + (((kk*4 + lk) ^ (row & 7)) << 3);
        ah[mi] = *(const bf16x8*)&Ahi[idx];
        al[mi] = *(const bf16x8*)&Alo[idx];
      }
#pragma unroll
      for (int nj = 0; nj < FN; nj++){
        int col = wc*WNT + nj*16 + lr;
        int idx = col*64 + (((kk*4 + lk) ^ (col & 7)) << 3);
        bh[nj] = *(const bf16x8*)&Bhi[idx];
        bl[nj] = *(const bf16x8*)&Blo[idx];
      }
#pragma unroll
      for (int mi = 0; mi < FM; mi++)
#pragma unroll
        for (int nj = 0; nj < FN; nj++){
          acc[mi][nj] = __builtin_amdgcn_mfma_f32_16x16x32_bf16(ah[mi], bh[nj], acc[mi][nj], 0, 0, 0);
          acc[mi][nj] = __builtin_amdgcn_mfma_f32_16x16x32_bf16(ah[mi], bl[nj], acc[mi][nj], 0, 0, 0);
          acc[mi][nj] = __builtin_amdgcn_mfma_f32_16x16x32_bf16(al[mi], bh[nj], acc[mi][nj], 0, 0, 0);
        }
    }
    __syncthreads();
  }

  // epilogue
  const float* wz  = nullptr;
  const float* cqz = nullptr; const float* ckz = nullptr;
  if constexpr (EPI == 3) wz = wcolp + (long)z*512;
  if constexpr (EPI == 4){ cqz = cqp + (long)zb*16384 + zh*4; ckz = ckp + (long)zb*16384 + zh*4; }
  const float* bp = bias;
  if constexpr (QKV) bp = (zb == 0) ? bias : ((zb == 1) ? bias1 : bias2);

  float4 ckv[FN];
  if constexpr (EPI == 4){
#pragma unroll
    for (int nj = 0; nj < FN; nj++){
      int gcol = n0 + wc*WNT + nj*16 + lr;
      ckv[nj] = *(const float4*)(ckz + (long)gcol*32);
    }
  }
#pragma unroll
  for (int mi = 0; mi < FM; mi++){
#pragma unroll
    for (int r = 0; r < 4; r++){
      int grow = m0 + wr*WMT + mi*16 + lk*4 + r;
      float* crow = Cb + (long)grow*ldc;
      float4 cqv;
      if constexpr (EPI == 4) cqv = *(const float4*)(cqz + (long)grow*32);
#pragma unroll
      for (int nj = 0; nj < FN; nj++){
        int gcol = n0 + wc*WNT + nj*16 + lr;
        float v = acc[mi][nj][r];
        if constexpr (EPI == 1) v += bp[gcol];
        if constexpr (EPI == 2) v += crow[gcol];
        if constexpr (EPI == 3) v *= wz[gcol];
        if constexpr (EPI == 4)
          v *= 0.125f*(cqv.x*ckv[nj].x + cqv.y*ckv[nj].y + cqv.z*ckv[nj].z + cqv.w*ckv[nj].w);
        crow[gcol] = v;
      }
    }
  }
}

// ---------------------------------------------------------------------------
// Weight transpose + bf16 hi/lo convert: W[512][512] -> Wt_hi/lo [n][k]
// ---------------------------------------------------------------------------
__global__ __launch_bounds__(256)
void wconv_t(const float* __restrict__ W0, const float* __restrict__ W1,
             const float* __restrict__ W2, const float* __restrict__ W3,
             short* H0, short* L0, short* H1, short* L1,
             short* H2, short* L2, short* H3, short* L3)
{
  const float* W; short* Hh; short* Ll;
  switch (blockIdx.z){
    case 0:  W = W0; Hh = H0; Ll = L0; break;
    case 1:  W = W1; Hh = H1; Ll = L1; break;
    case 2:  W = W2; Hh = H2; Ll = L2; break;
    default: W = W3; Hh = H3; Ll = L3; break;
  }
  __shared__ float s[64][65];
  const int r0 = blockIdx.y*64, c0 = blockIdx.x*64;
  const int t = threadIdx.x;
#pragma unroll
  for (int i = 0; i < 4; i++){
    int idx = t + i*256;                 // 1024 float4 slots
    int r = idx >> 4, c4 = (idx & 15)*4;
    float4 v = *(const float4*)(W + (long)(r0 + r)*512 + c0 + c4);
    s[r][c4+0] = v.x; s[r][c4+1] = v.y; s[r][c4+2] = v.z; s[r][c4+3] = v.w;
  }
  __syncthreads();
#pragma unroll
  for (int i = 0; i < 2; i++){
    int p = t + i*256;                   // 512: 64 n x 8 kb
    int n = p >> 3, kb = p & 7;
    float f[8];
#pragma unroll
    for (int j = 0; j < 8; j++) f[j] = s[kb*8 + j][n];
    uint4 H, L; cvt8(f, H, L);
    long off = (long)(c0 + n)*512 + r0 + kb*8;
    *(uint4*)&Hh[off] = H; *(uint4*)&Ll[off] = L;
  }
}

// ---------------------------------------------------------------------------
// Skinny projection: om = relu(X@Wom+bom), th = tanh(X@Wth+bth)*PI (8192x16 each)
// ---------------------------------------------------------------------------
__global__ __launch_bounds__(256)
void skinny_k(const float* __restrict__ X,
              const float* __restrict__ Wom, const float* __restrict__ bom,
              const float* __restrict__ Wth, const float* __restrict__ bth,
              float* __restrict__ om_out, float* __restrict__ th_out)
{
    const int t = threadIdx.x;
    const int tx = t & 31, ty = t >> 5;
    const long row = (long)blockIdx.x * 8 + ty;
    const int col = tx & 15;
    const bool isTh = tx >= 16;
    const float* __restrict__ Wm = isTh ? Wth : Wom;
    const float* __restrict__ xr = X + row * 512;
    float acc0 = 0.f, acc1 = 0.f, acc2 = 0.f, acc3 = 0.f;
    for (int k = 0; k < 512; k += 4) {
        acc0 += xr[k + 0] * Wm[(k + 0) * 16 + col];
        acc1 += xr[k + 1] * Wm[(k + 1) * 16 + col];
        acc2 += xr[k + 2] * Wm[(k + 2) * 16 + col];
        acc3 += xr[k + 3] * Wm[(k + 3) * 16 + col];
    }
    float acc = (acc0 + acc1) + (acc2 + acc3);
    if (isTh) {
        acc += bth[col];
        th_out[row * 16 + col] = tanhf(acc) * PI_F;
    } else {
        acc += bom[col];
        om_out[row * 16 + col] = fmaxf(acc, 0.f);
    }
}

// ---------------------------------------------------------------------------
__global__ __launch_bounds__(256)
void phases_k(const float* __restrict__ om, const float* __restrict__ th,
              float* __restrict__ C)
{
    const int i = blockIdx.x * 256 + threadIdx.x;   // (b*512+l)*8 + h
    if (i >= 65536) return;
    const float tt = (float)((i >> 3) & 511);
    const float o0 = om[i * 2 + 0], o1 = om[i * 2 + 1];
    const float t0 = th[i * 2 + 0], t1 = th[i * 2 + 1];
    float c0, s0, c1, s1;
    sincosf(o0 * tt + t0, &s0, &c0);
    sincosf(o1 * tt + t1, &s1, &c1);
    float4 r = { c0, s0, c1, s1 };
    *(float4*)&C[(long)i * 4] = r;
}

// ---------------------------------------------------------------------------
template<int MODE>
__global__ __launch_bounds__(256)
void movavg_k(const float* __restrict__ X, float* __restrict__ RES,
              float* __restrict__ TREND)
{
    const int b = blockIdx.z, l0 = blockIdx.y * 64, c0 = blockIdx.x * 64;
    __shared__ float sm[88][64];
    const float* __restrict__ Xb = X + (long)b * 512 * 512 + c0;
    const int t = threadIdx.x;
    for (int i = t; i < 88 * 64; i += 256) {
        const int r = i >> 6, c = i & 63;
        int gl = l0 + r - 12;
        gl = min(max(gl, 0), 511);
        sm[r][c] = Xb[(long)gl * 512 + c];
    }
    __syncthreads();
    const int tx = t & 63, ty = t >> 6;
    const int rbase = ty * 16;
    float s = 0.f;
    #pragma unroll
    for (int d = 0; d < 25; d++) s += sm[rbase + d][tx];
    const float inv = 1.f / 25.f;
    #pragma unroll
    for (int r = 0; r < 16; r++) {
        const long l = l0 + rbase + r;
        const float ma = s * inv;
        const float x = sm[rbase + r + 12][tx];
        RES[((long)b * 512 + l) * 512 + c0 + tx] = x - ma;
        if (MODE) TREND[((long)b * 512 + l) * 512 + c0 + tx] = ma;
        if (r < 15) s += sm[rbase + r + 25][tx] - sm[rbase + r][tx];
    }
}

// ---------------------------------------------------------------------------
__global__ __launch_bounds__(256)
void softmax_k(float* __restrict__ A)
{
    const long row = (long)blockIdx.x * 4 + (threadIdx.x >> 6);
    const int lane = threadIdx.x & 63;
    float* __restrict__ r = A + row * 512;
    float v[8];
    float m = -INFINITY;
    #pragma unroll
    for (int i = 0; i < 8; i++) { v[i] = r[lane + i * 64]; m = fmaxf(m, v[i]); }
    #pragma unroll
    for (int off = 32; off; off >>= 1) m = fmaxf(m, __shfl_xor(m, off));
    float s = 0.f;
    #pragma unroll
    for (int i = 0; i < 8; i++) { v[i] = __expf(v[i] - m); s += v[i]; }
    #pragma unroll
    for (int off = 32; off; off >>= 1) s += __shfl_xor(s, off);
    const float inv = 1.f / s;
    #pragma unroll
    for (int i = 0; i < 8; i++) r[lane + i * 64] = v[i] * inv;
}

// ---------------------------------------------------------------------------
__global__ __launch_bounds__(512)
void lamw_k(const float* __restrict__ VT, const float* __restrict__ Wlam,
            const float* __restrict__ blam, const float* __restrict__ Sv,
            float* __restrict__ Wout)
{
    const int z = blockIdx.x;                 // b*8+h
    const int b = z >> 3, h = z & 7;
    __shared__ float sv[512][17];
    __shared__ float sw[448];
    const int t = threadIdx.x;                // 512
    if (t < 448) sw[t] = Wlam[t];
    const float* __restrict__ Vb = VT + ((long)b * 512) * 512 + h * 64;
    float lam = 0.f;
    for (int ec = 0; ec < 4; ec++) {
        __syncthreads();
        #pragma unroll
        for (int j4 = 0; j4 < 4; j4++) {
            float4 v = *(const float4*)(Vb + (long)t * 512 + ec * 16 + j4 * 4);
            sv[t][j4 * 4 + 0] = v.x; sv[t][j4 * 4 + 1] = v.y;
            sv[t][j4 * 4 + 2] = v.z; sv[t][j4 * 4 + 3] = v.w;
        }
        __syncthreads();
        #pragma unroll
        for (int dk = 0; dk < 7; dk++) {
            int r = t + dk - 3;
            r = min(max(r, 0), 511);
            #pragma unroll
            for (int j = 0; j < 16; j++)
                lam += sv[r][j] * sw[(ec * 16 + j) * 7 + dk];
        }
    }
    lam += blam[0];
    const float el = lam > 0.f ? lam : expm1f(lam);
    const float wv = 1.f / (1.f + (1.f + el) * Sv[t]);
    Wout[(long)z * 512 + t] = wv;
}

// ---------------------------------------------------------------------------
__global__ __launch_bounds__(256)
void pen1_k(const float* __restrict__ qom, const float* __restrict__ kom,
            const float* __restrict__ qth, const float* __restrict__ kth,
            float* __restrict__ partials)
{
    const long tid = (long)blockIdx.x * 256 + threadIdx.x;   // 65536 threads
    float om = 0.f, th = 0.f;
    for (long i = tid; i < 262144; i += 65536) {
        const float* om_arr = (i < 131072) ? qom : kom;
        const float* th_arr = (i < 131072) ? qth : kth;
        const long j = i & 131071;
        const float x = th_arr[j];
        th += x * x;
        const int l = (int)((j >> 4) & 511);
        if (l < 511) {
            const float d = om_arr[j + 16] - om_arr[j];
            om += d * d;
        }
    }
    __shared__ float som[256], sth[256];
    som[threadIdx.x] = om; sth[threadIdx.x] = th;
    __syncthreads();
    for (int o = 128; o; o >>= 1) {
        if (threadIdx.x < o) {
            som[threadIdx.x] += som[threadIdx.x + o];
            sth[threadIdx.x] += sth[threadIdx.x + o];
        }
        __syncthreads();
    }
    if (threadIdx.x == 0) {
        partials[blockIdx.x] = som[0];
        partials[256 + blockIdx.x] = sth[0];
    }
}

__global__ __launch_bounds__(256)
void pen2_k(const float* __restrict__ partials, float* __restrict__ om_out,
            float* __restrict__ th_out)
{
    __shared__ float som[256], sth[256];
    const int t = threadIdx.x;
    som[t] = partials[t]; sth[t] = partials[256 + t];
    __syncthreads();
    for (int o = 128; o; o >>= 1) {
        if (t < o) { som[t] += som[t + o]; sth[t] += sth[t + o]; }
        __syncthreads();
    }
    if (t == 0) { *om_out = som[0]; *th_out = sth[0]; }
}

// ---------------------------------------------------------------------------
extern "C" void kernel_launch(void* const* d_in, const int* in_sizes, int n_in,
                              void* d_out_v, int out_size, void* d_ws, size_t ws_size,
                              hipStream_t stream)
{
    const float* queries = (const float*)d_in[0];
    const float* keys    = (const float*)d_in[1];
    const float* values  = (const float*)d_in[2];
    const float* Wq  = (const float*)d_in[3];  const float* bq  = (const float*)d_in[4];
    const float* Wk  = (const float*)d_in[5];  const float* bk  = (const float*)d_in[6];
    const float* Wv  = (const float*)d_in[7];  const float* bv  = (const float*)d_in[8];
    const float* Wqo = (const float*)d_in[9];  const float* bqo = (const float*)d_in[10];
    const float* Wko = (const float*)d_in[11]; const float* bko = (const float*)d_in[12];
    const float* Wqt = (const float*)d_in[13]; const float* bqt = (const float*)d_in[14];
    const float* Wkt = (const float*)d_in[15]; const float* bkt = (const float*)d_in[16];
    const float* Wo  = (const float*)d_in[17]; const float* bo  = (const float*)d_in[18];
    const float* Wlam= (const float*)d_in[19]; const float* blam= (const float*)d_in[20];
    const float* U   = (const float*)d_in[21]; const float* Sv  = (const float*)d_in[22];

    float* out = (float*)d_out_v;
    float* W   = (float*)d_ws;

    // workspace layout (float units)
    float* q_proj  = W;                    // 4194304 (later reused as T1t)
    float* k_proj  = W + 4194304;          // (later reused as attn_out)
    float* v_proj  = W + 8388608;
    float* q_res   = W + 12582912;
    float* k_res   = W + 16777216;
    float* v_res   = W + 20971520;
    float* v_trend = W + 25165824;
    float* T1t      = q_proj;              // [128][64][512] f32
    float* attn_out = k_proj;              // [16][512][512] f32
    float* q_om = W + 29360128;
    float* k_om = q_om + 131072;
    float* q_th = k_om + 131072;
    float* k_th = q_th + 131072;
    float* Cq   = k_th + 131072;           // 262144
    float* Ck   = Cq + 262144;             // 262144
    float* wbuf = Ck + 262144;             // 65536
    float* partials = wbuf + 65536;        // 1024
    short* wsp = (short*)(W + 30475264);   // 4 weights x (hi 262144 + lo 262144 shorts)
    short* WqH = wsp;            short* WqL = wsp + 262144;
    short* WkH = wsp + 524288;   short* WkL = wsp + 786432;
    short* WvH = wsp + 1048576;  short* WvL = wsp + 1310720;
    short* WoH = wsp + 1572864;  short* WoL = wsp + 1835008;

    float* attn = out + ATTN_OFF;
    dim3 blk(256);

    // 0. weight transpose + bf16 hi/lo pre-pass
    wconv_t<<<dim3(8,8,4), blk, 0, stream>>>(Wq, Wk, Wv, Wo,
        WqH, WqL, WkH, WkL, WvH, WvL, WoH, WoL);

    // 1. fused QKV projection: z=0..2 -> {queries@Wq+bq, keys@Wk+bk, values@Wv+bv}
    mgemm<128,128,2,2,false,false,true,true,1><<<dim3(4,64,3), blk, 0, stream>>>(
        512, queries, keys, values, 512, 0, 0,
        nullptr, 0, 0, 0, WqH, WqL,
        q_proj, 512, 4194304, 0,
        bq, bk, bv, nullptr, nullptr, nullptr, 1);

    // 2. omega/theta skinny projections + phase tables
    skinny_k<<<dim3(1024), blk, 0, stream>>>(queries, Wqo, bqo, Wqt, bqt, q_om, q_th);
    skinny_k<<<dim3(1024), blk, 0, stream>>>(keys,    Wko, bko, Wkt, bkt, k_om, k_th);
    phases_k<<<dim3(256), blk, 0, stream>>>(q_om, q_th, Cq);
    phases_k<<<dim3(256), blk, 0, stream>>>(k_om, k_th, Ck);

    // 3. series decomposition
    movavg_k<0><<<dim3(8,8,16), blk, 0, stream>>>(q_proj, q_res, nullptr);
    movavg_k<0><<<dim3(8,8,16), blk, 0, stream>>>(k_proj, k_res, nullptr);
    movavg_k<1><<<dim3(8,8,16), blk, 0, stream>>>(v_proj, v_res, v_trend);

    // 4. scores = (q.k) * (Cq.Ck) / 8  -> attn region of d_out
    mgemm<128,128,2,2,false,false,false,false,4><<<dim3(4,4,128), blk, 0, stream>>>(
        64, q_res, nullptr, nullptr, 512, 262144, 64,
        k_res, 512, 262144, 64, nullptr, nullptr,
        attn, 512, 2097152, 262144,
        nullptr, nullptr, nullptr, nullptr, Cq, Ck, 8);

    // 5. softmax in place
    softmax_k<<<dim3(16384), blk, 0, stream>>>(attn);

    // 6. attn @ v_res -> attn_out
    mgemm<128,64,2,2,false,true,false,false,0><<<dim3(1,4,128), blk, 0, stream>>>(
        512, attn, nullptr, nullptr, 512, 2097152, 262144,
        v_res, 512, 262144, 64, nullptr, nullptr,
        attn_out, 512, 262144, 64,
        nullptr, nullptr, nullptr, nullptr, nullptr, nullptr, 8);

    // 7. lambda conv -> w
    lamw_k<<<dim3(128), dim3(512), 0, stream>>>(v_trend, Wlam, blam, Sv, wbuf);

    // 8. T1t[e][i] = ((U^T v_trend)^T)[e][i] * w[z][i]
    mgemm<64,128,2,2,true,true,false,false,3><<<dim3(4,1,128), blk, 0, stream>>>(
        512, v_trend, nullptr, nullptr, 512, 262144, 64,
        U, 512, 0, 0, nullptr, nullptr,
        T1t, 512, 262144, 32768,
        nullptr, nullptr, nullptr, wbuf, nullptr, nullptr, 8);

    // 9. attn_out += U @ T1  (B[k=i][col=e] = T1t[e][i])
    mgemm<128,64,2,2,false,false,false,false,2><<<dim3(1,4,128), blk, 0, stream>>>(
        512, U, nullptr, nullptr, 512, 0, 0,
        T1t, 512, 262144, 32768, nullptr, nullptr,
        attn_out, 512, 262144, 64,
        nullptr, nullptr, nullptr, nullptr, nullptr, nullptr, 8);

    // 10. out projection
    mgemm<64,128,2,2,false,false,true,false,1><<<dim3(4,128,1), blk, 0, stream>>>(
        512, attn_out, nullptr, nullptr, 512, 0, 0,
        nullptr, 0, 0, 0, WoH, WoL,
        out, 512, 0, 0,
        bo, nullptr, nullptr, nullptr, nullptr, nullptr, 1);

    // 11. penalties (deterministic)
    pen1_k<<<dim3(256), blk, 0, stream>>>(q_om, k_om, q_th, k_th, partials);
    pen2_k<<<dim3(1), blk, 0, stream>>>(partials, out + OM_OFF, out + TH_OFF);
}